// Round 3
// baseline (146.841 us; speedup 1.0000x reference)
//
#include <hip/hip_runtime.h>
#include <hip/hip_bf16.h>

using ushort = unsigned short;

typedef __attribute__((ext_vector_type(8))) short bf16x8;
typedef __attribute__((ext_vector_type(4))) short bf16x4;
typedef __attribute__((ext_vector_type(4))) float f32x4;
typedef __attribute__((ext_vector_type(4))) unsigned short u16x4;

#define DEVINL __device__ __forceinline__

// ---- problem constants ----
// B=2, S=2048, D=1024, H=16, dk=64, M=B*S=4096

// workspace layout (ushort element offsets)
static constexpr size_t XQ_O = 0;              // 4M elems (bf16 of query_tensor) -- reused as CTX later
static constexpr size_t XK_O = 4194304;
static constexpr size_t XV_O = 8388608;
static constexpr size_t WQ_O = 12582912;       // 1M each
static constexpr size_t WK_O = 13631488;
static constexpr size_t WV_O = 14680064;
static constexpr size_t WO_O = 15728640;
static constexpr size_t QB_O = 16777216;       // Q [b][h][s][64]   4M  (scaled by log2e/8)
static constexpr size_t KB_O = 20971520;       // K [b][h][s][64]   4M
static constexpr size_t VT_O = 25165824;       // V^T [b][h][64][s] 4M
static constexpr size_t CTX_O = 0;             // ctx [b][s][1024] reuses XQ

DEVINL ushort f2bf(float f) {
  unsigned u = __builtin_bit_cast(unsigned, f);
  u += 0x7fffu + ((u >> 16) & 1u);   // RNE
  return (ushort)(u >> 16);
}

DEVINL ushort f2bf_hw(float f) {
  __hip_bfloat16 h = __float2bfloat16(f);   // compiler emits v_cvt_pk_bf16_f32 for pairs (m240)
  return *reinterpret_cast<ushort*>(&h);
}

// ---------------- fp32 -> bf16 conversion of all inputs ----------------
__global__ __launch_bounds__(256) void cvt_all(
    const float* __restrict__ xq, const float* __restrict__ xk, const float* __restrict__ xv,
    const float* __restrict__ wq, const float* __restrict__ wk, const float* __restrict__ wv,
    const float* __restrict__ wo, ushort* __restrict__ ws)
{
  int e = (blockIdx.x * 256 + threadIdx.x) * 8;   // 16M elems total
  const float* s;
  if      (e < 4194304)  s = xq + e;
  else if (e < 8388608)  s = xk + (e - 4194304);
  else if (e < 12582912) s = xv + (e - 8388608);
  else if (e < 13631488) s = wq + (e - 12582912);
  else if (e < 14680064) s = wk + (e - 13631488);
  else if (e < 15728640) s = wv + (e - 14680064);
  else                   s = wo + (e - 15728640);
  float4 a = *(const float4*)s;
  float4 b = *(const float4*)(s + 4);
  union { u16x4 v; ushort u[4]; } r0, r1;
  r0.u[0] = f2bf(a.x); r0.u[1] = f2bf(a.y); r0.u[2] = f2bf(a.z); r0.u[3] = f2bf(a.w);
  r1.u[0] = f2bf(b.x); r1.u[1] = f2bf(b.y); r1.u[2] = f2bf(b.z); r1.u[3] = f2bf(b.w);
  *(u16x4*)(ws + e) = r0.v;
  *(u16x4*)(ws + e + 4) = r1.v;
}

// ---------------- 128x128 bf16 NT GEMM core (y = x @ W^T + b) ----------------
// A: [M][1024] bf16 row-major, Bw: [N][1024] bf16 row-major (N = output feature)
// omode 0: bf16 out -> [b][h][s][64]; 1: fp32 row-major [m][1024]; 2: bf16 -> [b][h][64][s]
DEVINL void gemm_core(const ushort* __restrict__ A, const ushort* __restrict__ Bw,
                      const float* __restrict__ bias, void* __restrict__ Cout,
                      float scale, int omode, int row0, int col0)
{
  constexpr int K = 1024;
  __shared__ ushort As[128 * 64];
  __shared__ ushort Bs[128 * 64];
  const int t = threadIdx.x;
  const int l = t & 63;
  const int w = t >> 6;
  const int wr = w >> 1, wc = w & 1;

  const int srow = t >> 3;
  const int scol8 = (t & 7) * 8;
  const int swz_half = ((((t & 7) * 16) ^ ((srow & 7) << 4)) >> 1);

  const ushort* Ap = A + (size_t)(row0 + srow) * K + scol8;
  const ushort* Bp = Bw + (size_t)(col0 + srow) * K + scol8;

  bf16x8 areg[4], breg[4];
  auto loadstage = [&](int k0) {
#pragma unroll
    for (int i = 0; i < 4; ++i) {
      areg[i] = *(const bf16x8*)(Ap + (size_t)(i * 32) * K + k0);
      breg[i] = *(const bf16x8*)(Bp + (size_t)(i * 32) * K + k0);
    }
  };

  f32x4 acc[4][4];
#pragma unroll
  for (int i = 0; i < 4; ++i)
#pragma unroll
    for (int j = 0; j < 4; ++j) acc[i][j] = (f32x4){0.f, 0.f, 0.f, 0.f};

  loadstage(0);
#pragma unroll 1
  for (int kt = 0; kt < K / 64; ++kt) {
    __syncthreads();
#pragma unroll
    for (int i = 0; i < 4; ++i) {
      *(bf16x8*)&As[(srow + i * 32) * 64 + swz_half] = areg[i];
      *(bf16x8*)&Bs[(srow + i * 32) * 64 + swz_half] = breg[i];
    }
    if (kt + 1 < K / 64) loadstage((kt + 1) * 64);
    __syncthreads();
#pragma unroll
    for (int ks = 0; ks < 2; ++ks) {
      bf16x8 af[4], bfr[4];
#pragma unroll
      for (int mi = 0; mi < 4; ++mi) {
        int r = wr * 64 + mi * 16 + (l & 15);
        int cb = ((ks << 6) | ((l >> 4) << 4)) ^ ((r & 7) << 4);
        af[mi] = *(const bf16x8*)&As[r * 64 + (cb >> 1)];
      }
#pragma unroll
      for (int nj = 0; nj < 4; ++nj) {
        int r = wc * 64 + nj * 16 + (l & 15);
        int cb = ((ks << 6) | ((l >> 4) << 4)) ^ ((r & 7) << 4);
        bfr[nj] = *(const bf16x8*)&Bs[r * 64 + (cb >> 1)];
      }
#pragma unroll
      for (int mi = 0; mi < 4; ++mi)
#pragma unroll
        for (int nj = 0; nj < 4; ++nj)
          acc[mi][nj] = __builtin_amdgcn_mfma_f32_16x16x32_bf16(af[mi], bfr[nj], acc[mi][nj], 0, 0, 0);
    }
  }

  // epilogue: D layout col = lane&15, row = (lane>>4)*4 + reg
  const int cl = l & 15;
#pragma unroll
  for (int mi = 0; mi < 4; ++mi) {
#pragma unroll
    for (int nj = 0; nj < 4; ++nj) {
      int n = col0 + wc * 64 + nj * 16 + cl;
      float bv = bias[n];
      int mbase = row0 + wr * 64 + mi * 16 + (l >> 4) * 4;
      if (omode == 1) {
        float* Of = (float*)Cout;
#pragma unroll
        for (int ri = 0; ri < 4; ++ri)
          Of[(size_t)(mbase + ri) * 1024 + n] = (acc[mi][nj][ri] + bv) * scale;
      } else if (omode == 0) {
        ushort* Ob = (ushort*)Cout;
        int h = n >> 6, d = n & 63;
#pragma unroll
        for (int ri = 0; ri < 4; ++ri) {
          int m = mbase + ri;
          int b = m >> 11, s = m & 2047;
          Ob[(size_t)((b * 16 + h) * 2048 + s) * 64 + d] = f2bf((acc[mi][nj][ri] + bv) * scale);
        }
      } else {  // omode 2: transposed V layout [b][h][d][s]
        ushort* Ob = (ushort*)Cout;
        int h = n >> 6, d = n & 63;
        int b = mbase >> 11, s = mbase & 2047;
        union { u16x4 v; ushort u[4]; } pk;
#pragma unroll
        for (int ri = 0; ri < 4; ++ri) pk.u[ri] = f2bf((acc[mi][nj][ri] + bv) * scale);
        *(u16x4*)&Ob[(size_t)((b * 16 + h) * 64 + d) * 2048 + s] = pk.v;
      }
    }
  }
}

// fused QKV projection: blockIdx.z selects q/k/v
__global__ __launch_bounds__(256, 2) void gemm_qkv(
    const ushort* __restrict__ ws_c, ushort* __restrict__ ws_m,
    const float* __restrict__ bq, const float* __restrict__ bk, const float* __restrict__ bv)
{
  const int z = blockIdx.z;
  const ushort* A = ws_c + XQ_O + (size_t)z * 4194304;
  const ushort* W = ws_c + WQ_O + (size_t)z * 1048576;
  const float* bias = (z == 0) ? bq : ((z == 1) ? bk : bv);
  ushort* dst = ws_m + QB_O + (size_t)z * 4194304;
  // fold 1/sqrt(dk) AND log2(e) into Q so softmax uses exp2 directly
  float scale = (z == 0) ? (0.125f * 1.4426950408889634f) : 1.0f;
  int omode = (z == 2) ? 2 : 0;
  gemm_core(A, W, bias, dst, scale, omode, blockIdx.y * 128, blockIdx.x * 128);
}

__global__ __launch_bounds__(256, 2) void gemm_out(
    const ushort* __restrict__ ctx, const ushort* __restrict__ wo,
    const float* __restrict__ bo, float* __restrict__ out)
{
  gemm_core(ctx, wo, bo, out, 1.0f, 1, blockIdx.y * 128, blockIdx.x * 128);
}

// ---------------- flash attention (swapped-QK^T, in-register softmax) ----------------
// grid: (qtile 0..31, bh 0..31), 256 threads = 4 waves; wave owns 16 q rows (QBLK=64).
// 1024 blocks -> 4 blocks/CU -> 4 waves/SIMD (vs 2 before): hides the softmax VALU/trans chain.
// S^T = mfma(K, Q): lane holds P^T[kv = kj*16+hi*4+ri][q = lane&15].
// PV uses a permuted contraction order: MFMA k-slot (hi,j) := kv 32*ks+16*(j>>2)+hi*4+(j&3),
// making the P^T B-fragment register-local and the V^T A-fragment two ds_read_b64.
__global__ __launch_bounds__(256, 4) void attn64(
    const ushort* __restrict__ Qb, const ushort* __restrict__ Kb,
    const ushort* __restrict__ Vtb, ushort* __restrict__ Ctx)
{
  __shared__ ushort Ks[128 * 64];      // [kv][dk] swizzled, 128B rows
  __shared__ ushort Vs[64 * 128];      // [d][kv]  swizzled, 256B rows

  const int t = threadIdx.x, l = t & 63, w = t >> 6;
  const int hi = l >> 4, q = l & 15;
  const int bh = blockIdx.y, qt = blockIdx.x;
  const ushort* Qp = Qb + ((size_t)bh * 2048 + qt * 64 + w * 16) * 64;
  const ushort* Kp = Kb + (size_t)bh * 2048 * 64;
  const ushort* Vp = Vtb + (size_t)bh * 64 * 2048;

  // Q fragments (B-operand): lane l -> col q=l&15, k-slice d = ks*32 + hi*8 + j
  bf16x8 qf[2];
#pragma unroll
  for (int ks = 0; ks < 2; ++ks)
    qf[ks] = *(const bf16x8*)(Qp + q * 64 + ks * 32 + hi * 8);

  const int krow = t >> 3;  const int kc8 = (t & 7) * 8;
  const int kswz = ((((t & 7) * 16) ^ ((krow & 7) << 4)) >> 1);
  const int vrow = t >> 4;  const int vc8 = (t & 15) * 8;
  const int vswz = ((((t & 15) * 16) ^ ((vrow & 7) << 4)) >> 1);

  bf16x8 kreg[4], vreg[4];
  auto loadKV = [&](int kv0) {
#pragma unroll
    for (int i = 0; i < 4; ++i) {
      kreg[i] = *(const bf16x8*)(Kp + (size_t)(kv0 + krow + i * 32) * 64 + kc8);
      vreg[i] = *(const bf16x8*)(Vp + (size_t)(vrow + i * 16) * 2048 + kv0 + vc8);
    }
  };

  f32x4 acc[4];   // O^T: row d = dj*16+hi*4+ri, col q = lane&15
#pragma unroll
  for (int dj = 0; dj < 4; ++dj) acc[dj] = (f32x4){0.f, 0.f, 0.f, 0.f};
  float mrun = -1e30f;
  float lrun = 0.f;

  loadKV(0);
#pragma unroll 1
  for (int kt = 0; kt < 16; ++kt) {
    __syncthreads();
#pragma unroll
    for (int i = 0; i < 4; ++i) {
      *(bf16x8*)&Ks[(krow + i * 32) * 64 + kswz] = kreg[i];
      *(bf16x8*)&Vs[(vrow + i * 16) * 128 + vswz] = vreg[i];
    }
    if (kt + 1 < 16) loadKV((kt + 1) * 128);
    __syncthreads();

    // ---- S^T = K Q^T (log2-domain scores; scale folded into Q) ----
    f32x4 sfr[8];
    __builtin_amdgcn_s_setprio(1);
#pragma unroll
    for (int kj = 0; kj < 8; ++kj) {
      int r = kj * 16 + q;
      int cb0 = ((hi << 4)) ^ ((r & 7) << 4);
      int cb1 = (64 + (hi << 4)) ^ ((r & 7) << 4);
      bf16x8 kf0 = *(const bf16x8*)&Ks[r * 64 + (cb0 >> 1)];
      bf16x8 kf1 = *(const bf16x8*)&Ks[r * 64 + (cb1 >> 1)];
      f32x4 z = (f32x4){0.f, 0.f, 0.f, 0.f};
      z = __builtin_amdgcn_mfma_f32_16x16x32_bf16(kf0, qf[0], z, 0, 0, 0);
      sfr[kj] = __builtin_amdgcn_mfma_f32_16x16x32_bf16(kf1, qf[1], z, 0, 0, 0);
    }
    __builtin_amdgcn_s_setprio(0);

    // ---- online softmax, lane-local + defer-max (T13, log2 domain, THR=12) ----
    {
      float p0 = sfr[0][0], p1 = sfr[0][1], p2 = sfr[0][2], p3 = sfr[0][3];
#pragma unroll
      for (int kj = 1; kj < 8; ++kj) {
        p0 = fmaxf(p0, sfr[kj][0]); p1 = fmaxf(p1, sfr[kj][1]);
        p2 = fmaxf(p2, sfr[kj][2]); p3 = fmaxf(p3, sfr[kj][3]);
      }
      float tm = fmaxf(fmaxf(p0, p1), fmaxf(p2, p3));
      tm = fmaxf(tm, __shfl_xor(tm, 16));
      tm = fmaxf(tm, __shfl_xor(tm, 32));
      if (!__all(tm - mrun <= 12.0f)) {
        float mnew = fmaxf(mrun, tm);
        float fsc = exp2f(mrun - mnew);
        mrun = mnew;
        lrun *= fsc;
#pragma unroll
        for (int dj = 0; dj < 4; ++dj) {
          acc[dj][0] *= fsc; acc[dj][1] *= fsc;
          acc[dj][2] *= fsc; acc[dj][3] *= fsc;
        }
      }
      float s0 = 0.f, s1 = 0.f, s2 = 0.f, s3 = 0.f;
#pragma unroll
      for (int kj = 0; kj < 8; ++kj) {
        float e0 = exp2f(sfr[kj][0] - mrun); sfr[kj][0] = e0; s0 += e0;
        float e1 = exp2f(sfr[kj][1] - mrun); sfr[kj][1] = e1; s1 += e1;
        float e2 = exp2f(sfr[kj][2] - mrun); sfr[kj][2] = e2; s2 += e2;
        float e3 = exp2f(sfr[kj][3] - mrun); sfr[kj][3] = e3; s3 += e3;
      }
      lrun += (s0 + s1) + (s2 + s3);
    }

    // ---- O^T += V^T P^T (permuted contraction; P stays in registers) ----
    __builtin_amdgcn_s_setprio(1);
#pragma unroll
    for (int ks = 0; ks < 4; ++ks) {
      union VU { bf16x8 v; bf16x4 h[2]; } vf[4];
#pragma unroll
      for (int dj = 0; dj < 4; ++dj) {
        int d = dj * 16 + q;
#pragma unroll
        for (int jh = 0; jh < 2; ++jh) {
          int bb = (64 * ks + 32 * jh + hi * 8) ^ ((d & 7) << 4);
          vf[dj].h[jh] = *(const bf16x4*)&Vs[d * 128 + (bb >> 1)];
        }
      }
      union PU { bf16x8 v; ushort u[8]; } pb;
#pragma unroll
      for (int j = 0; j < 8; ++j)
        pb.u[j] = f2bf_hw(sfr[2 * ks + (j >> 2)][j & 3]);
#pragma unroll
      for (int dj = 0; dj < 4; ++dj)
        acc[dj] = __builtin_amdgcn_mfma_f32_16x16x32_bf16(vf[dj].v, pb.v, acc[dj], 0, 0, 0);
    }
    __builtin_amdgcn_s_setprio(0);
  }

  // ---- finalize: divide by row sum, write ctx [b][s][1024] (8B packed stores) ----
  const int b = bh >> 4, h = bh & 15;
  {
    float ls = lrun;
    ls += __shfl_xor(ls, 16);
    ls += __shfl_xor(ls, 32);
    float inv = 1.0f / ls;
    int sg = qt * 64 + w * 16 + q;
    ushort* dst = Ctx + ((size_t)b * 2048 + sg) * 1024 + h * 64;
#pragma unroll
    for (int dj = 0; dj < 4; ++dj) {
      union { u16x4 v; ushort u[4]; } pk;
#pragma unroll
      for (int ri = 0; ri < 4; ++ri)
        pk.u[ri] = f2bf_hw(acc[dj][ri] * inv);
      *(u16x4*)(dst + dj * 16 + hi * 4) = pk.v;
    }
  }
}

extern "C" void kernel_launch(void* const* d_in, const int* in_sizes, int n_in,
                              void* d_out, int out_size, void* d_ws, size_t ws_size,
                              hipStream_t stream) {
  const float* xq = (const float*)d_in[0];
  const float* xk = (const float*)d_in[1];
  const float* xv = (const float*)d_in[2];
  const float* wq = (const float*)d_in[3];
  const float* bq = (const float*)d_in[4];
  const float* wk = (const float*)d_in[5];
  const float* bk = (const float*)d_in[6];
  const float* wv = (const float*)d_in[7];
  const float* bv = (const float*)d_in[8];
  const float* wo = (const float*)d_in[9];
  const float* bo = (const float*)d_in[10];
  ushort* ws = (ushort*)d_ws;

  cvt_all<<<8192, 256, 0, stream>>>(xq, xk, xv, wq, wk, wv, wo, ws);
  gemm_qkv<<<dim3(8, 32, 3), 256, 0, stream>>>(ws, ws, bq, bk, bv);
  attn64<<<dim3(32, 32), 256, 0, stream>>>(ws + QB_O, ws + KB_O, ws + VT_O, ws + CTX_O);
  gemm_out<<<dim3(8, 32), 256, 0, stream>>>(ws + CTX_O, ws + WO_O, bo, (float*)d_out);
}

// Round 4
// 140.801 us; speedup vs baseline: 1.0429x; 1.0429x over previous
//
#include <hip/hip_runtime.h>
#include <hip/hip_bf16.h>

using ushort = unsigned short;

typedef __attribute__((ext_vector_type(8))) short bf16x8;
typedef __attribute__((ext_vector_type(4))) short bf16x4;
typedef __attribute__((ext_vector_type(4))) float f32x4;
typedef __attribute__((ext_vector_type(16))) float f32x16;
typedef __attribute__((ext_vector_type(4))) unsigned short u16x4;

#define DEVINL __device__ __forceinline__

// ---- problem constants ----
// B=2, S=2048, D=1024, H=16, dk=64, M=B*S=4096

// workspace layout (ushort element offsets)
static constexpr size_t XQ_O = 0;              // 4M elems (bf16 of query_tensor) -- reused as CTX later
static constexpr size_t XK_O = 4194304;
static constexpr size_t XV_O = 8388608;
static constexpr size_t WQ_O = 12582912;       // 1M each
static constexpr size_t WK_O = 13631488;
static constexpr size_t WV_O = 14680064;
static constexpr size_t WO_O = 15728640;
static constexpr size_t QB_O = 16777216;       // Q [b][h][s][64]   4M  (scaled by log2e/8)
static constexpr size_t KB_O = 20971520;       // K [b][h][s][64]   4M
static constexpr size_t VT_O = 25165824;       // V^T [b][h][64][s] 4M
static constexpr size_t CTX_O = 0;             // ctx [b][s][1024] reuses XQ

DEVINL ushort f2bf(float f) {
  unsigned u = __builtin_bit_cast(unsigned, f);
  u += 0x7fffu + ((u >> 16) & 1u);   // RNE
  return (ushort)(u >> 16);
}

DEVINL ushort f2bf_hw(float f) {
  __hip_bfloat16 h = __float2bfloat16(f);   // compiler emits v_cvt_pk_bf16_f32 for pairs (m240)
  return *reinterpret_cast<ushort*>(&h);
}

// ---------------- fp32 -> bf16 conversion of all inputs ----------------
__global__ __launch_bounds__(256) void cvt_all(
    const float* __restrict__ xq, const float* __restrict__ xk, const float* __restrict__ xv,
    const float* __restrict__ wq, const float* __restrict__ wk, const float* __restrict__ wv,
    const float* __restrict__ wo, ushort* __restrict__ ws)
{
  int e = (blockIdx.x * 256 + threadIdx.x) * 8;   // 16M elems total
  const float* s;
  if      (e < 4194304)  s = xq + e;
  else if (e < 8388608)  s = xk + (e - 4194304);
  else if (e < 12582912) s = xv + (e - 8388608);
  else if (e < 13631488) s = wq + (e - 12582912);
  else if (e < 14680064) s = wk + (e - 13631488);
  else if (e < 15728640) s = wv + (e - 14680064);
  else                   s = wo + (e - 15728640);
  float4 a = *(const float4*)s;
  float4 b = *(const float4*)(s + 4);
  union { u16x4 v; ushort u[4]; } r0, r1;
  r0.u[0] = f2bf(a.x); r0.u[1] = f2bf(a.y); r0.u[2] = f2bf(a.z); r0.u[3] = f2bf(a.w);
  r1.u[0] = f2bf(b.x); r1.u[1] = f2bf(b.y); r1.u[2] = f2bf(b.z); r1.u[3] = f2bf(b.w);
  *(u16x4*)(ws + e) = r0.v;
  *(u16x4*)(ws + e + 4) = r1.v;
}

// ---------------- 128x128 bf16 NT GEMM core (y = x @ W^T + b) ----------------
DEVINL void gemm_core(const ushort* __restrict__ A, const ushort* __restrict__ Bw,
                      const float* __restrict__ bias, void* __restrict__ Cout,
                      float scale, int omode, int row0, int col0)
{
  constexpr int K = 1024;
  __shared__ ushort As[128 * 64];
  __shared__ ushort Bs[128 * 64];
  const int t = threadIdx.x;
  const int l = t & 63;
  const int w = t >> 6;
  const int wr = w >> 1, wc = w & 1;

  const int srow = t >> 3;
  const int scol8 = (t & 7) * 8;
  const int swz_half = ((((t & 7) * 16) ^ ((srow & 7) << 4)) >> 1);

  const ushort* Ap = A + (size_t)(row0 + srow) * K + scol8;
  const ushort* Bp = Bw + (size_t)(col0 + srow) * K + scol8;

  bf16x8 areg[4], breg[4];
  auto loadstage = [&](int k0) {
#pragma unroll
    for (int i = 0; i < 4; ++i) {
      areg[i] = *(const bf16x8*)(Ap + (size_t)(i * 32) * K + k0);
      breg[i] = *(const bf16x8*)(Bp + (size_t)(i * 32) * K + k0);
    }
  };

  f32x4 acc[4][4];
#pragma unroll
  for (int i = 0; i < 4; ++i)
#pragma unroll
    for (int j = 0; j < 4; ++j) acc[i][j] = (f32x4){0.f, 0.f, 0.f, 0.f};

  loadstage(0);
#pragma unroll 1
  for (int kt = 0; kt < K / 64; ++kt) {
    __syncthreads();
#pragma unroll
    for (int i = 0; i < 4; ++i) {
      *(bf16x8*)&As[(srow + i * 32) * 64 + swz_half] = areg[i];
      *(bf16x8*)&Bs[(srow + i * 32) * 64 + swz_half] = breg[i];
    }
    if (kt + 1 < K / 64) loadstage((kt + 1) * 64);
    __syncthreads();
#pragma unroll
    for (int ks = 0; ks < 2; ++ks) {
      bf16x8 af[4], bfr[4];
#pragma unroll
      for (int mi = 0; mi < 4; ++mi) {
        int r = wr * 64 + mi * 16 + (l & 15);
        int cb = ((ks << 6) | ((l >> 4) << 4)) ^ ((r & 7) << 4);
        af[mi] = *(const bf16x8*)&As[r * 64 + (cb >> 1)];
      }
#pragma unroll
      for (int nj = 0; nj < 4; ++nj) {
        int r = wc * 64 + nj * 16 + (l & 15);
        int cb = ((ks << 6) | ((l >> 4) << 4)) ^ ((r & 7) << 4);
        bfr[nj] = *(const bf16x8*)&Bs[r * 64 + (cb >> 1)];
      }
#pragma unroll
      for (int mi = 0; mi < 4; ++mi)
#pragma unroll
        for (int nj = 0; nj < 4; ++nj)
          acc[mi][nj] = __builtin_amdgcn_mfma_f32_16x16x32_bf16(af[mi], bfr[nj], acc[mi][nj], 0, 0, 0);
    }
  }

  const int cl = l & 15;
#pragma unroll
  for (int mi = 0; mi < 4; ++mi) {
#pragma unroll
    for (int nj = 0; nj < 4; ++nj) {
      int n = col0 + wc * 64 + nj * 16 + cl;
      float bv = bias[n];
      int mbase = row0 + wr * 64 + mi * 16 + (l >> 4) * 4;
      if (omode == 1) {
        float* Of = (float*)Cout;
#pragma unroll
        for (int ri = 0; ri < 4; ++ri)
          Of[(size_t)(mbase + ri) * 1024 + n] = (acc[mi][nj][ri] + bv) * scale;
      } else if (omode == 0) {
        ushort* Ob = (ushort*)Cout;
        int h = n >> 6, d = n & 63;
#pragma unroll
        for (int ri = 0; ri < 4; ++ri) {
          int m = mbase + ri;
          int b = m >> 11, s = m & 2047;
          Ob[(size_t)((b * 16 + h) * 2048 + s) * 64 + d] = f2bf((acc[mi][nj][ri] + bv) * scale);
        }
      } else {  // omode 2: transposed V layout [b][h][d][s]
        ushort* Ob = (ushort*)Cout;
        int h = n >> 6, d = n & 63;
        int b = mbase >> 11, s = mbase & 2047;
        union { u16x4 v; ushort u[4]; } pk;
#pragma unroll
        for (int ri = 0; ri < 4; ++ri) pk.u[ri] = f2bf((acc[mi][nj][ri] + bv) * scale);
        *(u16x4*)&Ob[(size_t)((b * 16 + h) * 64 + d) * 2048 + s] = pk.v;
      }
    }
  }
}

__global__ __launch_bounds__(256, 2) void gemm_qkv(
    const ushort* __restrict__ ws_c, ushort* __restrict__ ws_m,
    const float* __restrict__ bq, const float* __restrict__ bk, const float* __restrict__ bv)
{
  const int z = blockIdx.z;
  const ushort* A = ws_c + XQ_O + (size_t)z * 4194304;
  const ushort* W = ws_c + WQ_O + (size_t)z * 1048576;
  const float* bias = (z == 0) ? bq : ((z == 1) ? bk : bv);
  ushort* dst = ws_m + QB_O + (size_t)z * 4194304;
  float scale = (z == 0) ? (0.125f * 1.4426950408889634f) : 1.0f;  // fold 1/sqrt(dk)*log2e into Q
  int omode = (z == 2) ? 2 : 0;
  gemm_core(A, W, bias, dst, scale, omode, blockIdx.y * 128, blockIdx.x * 128);
}

__global__ __launch_bounds__(256, 2) void gemm_out(
    const ushort* __restrict__ ctx, const ushort* __restrict__ wo,
    const float* __restrict__ bo, float* __restrict__ out)
{
  gemm_core(ctx, wo, bo, out, 1.0f, 1, blockIdx.y * 128, blockIdx.x * 128);
}

// ---------------- flash attention: 32x32x16 MFMA, chunked softmax, dbuf LDS ----------------
// grid (16,32) = 512 blocks, 4 waves/block; wave owns 32 q-rows; KVBLK=128 staged, computed
// in 4 chunks of 32 kv (online softmax per chunk) so QK(c+1) MFMA overlaps softmax(c) VALU.
// S^T = mfma32(K, Q): lane holds P^T[kv = (reg&3)+8*(reg>>2)+4*hi2 + 32c][q = l&31].
// PV contraction permuted so P^T B-frag slice0 = regs 0-7, slice1 = regs 8-15 (register-local);
// V^T A-frag = 2x ds_read_b64 per slice. One barrier per tile (double-buffered staging).
__global__ __launch_bounds__(256, 2) void attn32(
    const ushort* __restrict__ Qb, const ushort* __restrict__ Kb,
    const ushort* __restrict__ Vtb, ushort* __restrict__ Ctx)
{
  __shared__ ushort Ks[2][128 * 64];   // [kv][dk] swizzled (^(row&7)<<4 on bytes), 128B rows
  __shared__ ushort Vs[2][64 * 128];   // [d][kv]  swizzled, 256B rows

  const int t = threadIdx.x, l = t & 63, w = t >> 6;
  const int hi2 = l >> 5, q = l & 31;
  const int bh = blockIdx.y, qt = blockIdx.x;
  const ushort* Qp = Qb + ((size_t)bh * 2048 + qt * 128 + w * 32) * 64;
  const ushort* Kp = Kb + (size_t)bh * 2048 * 64;
  const ushort* Vp = Vtb + (size_t)bh * 64 * 2048;

  // Q B-fragments: lane holds Q[q0+q][ks*16 + hi2*8 + j], j=0..7
  bf16x8 qf[4];
#pragma unroll
  for (int ks = 0; ks < 4; ++ks)
    qf[ks] = *(const bf16x8*)(Qp + q * 64 + ks * 16 + hi2 * 8);

  const int krow = t >> 3;  const int kc8 = (t & 7) * 8;
  const int kswz = ((((t & 7) * 16) ^ ((krow & 7) << 4)) >> 1);
  const int vrow = t >> 4;  const int vc8 = (t & 15) * 8;
  const int vswz = ((((t & 15) * 16) ^ ((vrow & 7) << 4)) >> 1);

  bf16x8 kreg[4], vreg[4];
  auto loadKV = [&](int kv0) {
#pragma unroll
    for (int i = 0; i < 4; ++i) {
      kreg[i] = *(const bf16x8*)(Kp + (size_t)(kv0 + krow + i * 32) * 64 + kc8);
      vreg[i] = *(const bf16x8*)(Vp + (size_t)(vrow + i * 16) * 2048 + kv0 + vc8);
    }
  };
  auto writeStage = [&](int pp) {
#pragma unroll
    for (int i = 0; i < 4; ++i) {
      *(bf16x8*)&Ks[pp][(krow + i * 32) * 64 + kswz] = kreg[i];
      *(bf16x8*)&Vs[pp][(vrow + i * 16) * 128 + vswz] = vreg[i];
    }
  };

  f32x16 acc0, acc1;   // O^T: d = db*32 + (reg&3)+8*(reg>>2)+4*hi2, col q
#pragma unroll
  for (int i = 0; i < 16; ++i) { acc0[i] = 0.f; acc1[i] = 0.f; }
  float mrun = -1e30f, lrun = 0.f;

  loadKV(0);
  writeStage(0);
  loadKV(128);
  __syncthreads();

#pragma unroll 1
  for (int kt = 0; kt < 16; ++kt) {
    const int p = kt & 1;
    const ushort* Kl = Ks[p];
    const ushort* Vl = Vs[p];

#pragma unroll
    for (int c = 0; c < 4; ++c) {
      // ---- S^T chunk = K(32 kv) x Q^T : 4 MFMA over d ----
      f32x16 sc;
#pragma unroll
      for (int i = 0; i < 16; ++i) sc[i] = 0.f;
      const int r = c * 32 + q;
      const int rsw = (r & 7) << 4;
      __builtin_amdgcn_s_setprio(1);
#pragma unroll
      for (int ks = 0; ks < 4; ++ks) {
        bf16x8 kf = *(const bf16x8*)&Kl[r * 64 + (((ks * 32 + hi2 * 16) ^ rsw) >> 1)];
        sc = __builtin_amdgcn_mfma_f32_32x32x16_bf16(kf, qf[ks], sc, 0, 0, 0);
      }
      __builtin_amdgcn_s_setprio(0);

      if (c == 0) {   // stage next tile (regs loaded last iter), prefetch tile+2
        if (kt < 15) writeStage(p ^ 1);
        if (kt < 14) loadKV((kt + 2) * 128);
      }

      // ---- online softmax on 16 regs (log2 domain), defer-max THR=12 ----
      {
        float t0 = fmaxf(sc[0], sc[1]),  t1 = fmaxf(sc[2], sc[3]);
        float t2 = fmaxf(sc[4], sc[5]),  t3 = fmaxf(sc[6], sc[7]);
        float t4 = fmaxf(sc[8], sc[9]),  t5 = fmaxf(sc[10], sc[11]);
        float t6 = fmaxf(sc[12], sc[13]), t7 = fmaxf(sc[14], sc[15]);
        float tm = fmaxf(fmaxf(fmaxf(t0, t1), fmaxf(t2, t3)),
                         fmaxf(fmaxf(t4, t5), fmaxf(t6, t7)));
        tm = fmaxf(tm, __shfl_xor(tm, 32));
        if (!__all(tm - mrun <= 12.0f)) {
          float mnew = fmaxf(mrun, tm);
          float fsc = exp2f(mrun - mnew);
          mrun = mnew; lrun *= fsc;
#pragma unroll
          for (int i = 0; i < 16; ++i) { acc0[i] *= fsc; acc1[i] *= fsc; }
        }
        float s0 = 0.f, s1 = 0.f, s2 = 0.f, s3 = 0.f;
#pragma unroll
        for (int i = 0; i < 4; ++i) {
          float e0 = exp2f(sc[i] - mrun);      sc[i] = e0;      s0 += e0;
          float e1 = exp2f(sc[4 + i] - mrun);  sc[4 + i] = e1;  s1 += e1;
          float e2 = exp2f(sc[8 + i] - mrun);  sc[8 + i] = e2;  s2 += e2;
          float e3 = exp2f(sc[12 + i] - mrun); sc[12 + i] = e3; s3 += e3;
        }
        lrun += (s0 + s1) + (s2 + s3);
      }

      // ---- pack P^T (register-local: slice0 = regs 0-7, slice1 = regs 8-15) ----
      union PU { bf16x8 v; ushort u[8]; } p0, p1;
#pragma unroll
      for (int j = 0; j < 8; ++j) { p0.u[j] = f2bf_hw(sc[j]); p1.u[j] = f2bf_hw(sc[8 + j]); }

      // ---- O^T += V^T P^T : 4 MFMA (2 d-blocks x 2 kv-slices) ----
      __builtin_amdgcn_s_setprio(1);
#pragma unroll
      for (int db = 0; db < 2; ++db) {
        const int d = db * 32 + q;
        const int dsw = (d & 7) << 4;
        union VU { bf16x8 v; bf16x4 h[2]; } va, vb;
        va.h[0] = *(const bf16x4*)&Vl[d * 128 + (((c * 64 + 8 * hi2) ^ dsw) >> 1)];
        va.h[1] = *(const bf16x4*)&Vl[d * 128 + (((c * 64 + 16 + 8 * hi2) ^ dsw) >> 1)];
        vb.h[0] = *(const bf16x4*)&Vl[d * 128 + (((c * 64 + 32 + 8 * hi2) ^ dsw) >> 1)];
        vb.h[1] = *(const bf16x4*)&Vl[d * 128 + (((c * 64 + 48 + 8 * hi2) ^ dsw) >> 1)];
        if (db == 0) {
          acc0 = __builtin_amdgcn_mfma_f32_32x32x16_bf16(va.v, p0.v, acc0, 0, 0, 0);
          acc0 = __builtin_amdgcn_mfma_f32_32x32x16_bf16(vb.v, p1.v, acc0, 0, 0, 0);
        } else {
          acc1 = __builtin_amdgcn_mfma_f32_32x32x16_bf16(va.v, p0.v, acc1, 0, 0, 0);
          acc1 = __builtin_amdgcn_mfma_f32_32x32x16_bf16(vb.v, p1.v, acc1, 0, 0, 0);
        }
      }
      __builtin_amdgcn_s_setprio(0);
    }
    __syncthreads();
  }

  // ---- finalize: divide by row sum, write ctx [b][s][1024] (8B packed stores) ----
  const int b = bh >> 4, h = bh & 15;
  float ls = lrun + __shfl_xor(lrun, 32);
  float inv = 1.0f / ls;
  const int sg = qt * 128 + w * 32 + q;
  ushort* dst = Ctx + ((size_t)b * 2048 + sg) * 1024 + h * 64;
#pragma unroll
  for (int db = 0; db < 2; ++db) {
#pragma unroll
    for (int g = 0; g < 4; ++g) {
      union { u16x4 v; ushort u[4]; } pk;
#pragma unroll
      for (int ri = 0; ri < 4; ++ri) {
        float v = (db == 0) ? acc0[g * 4 + ri] : acc1[g * 4 + ri];
        pk.u[ri] = f2bf_hw(v * inv);
      }
      *(u16x4*)(dst + db * 32 + g * 8 + hi2 * 4) = pk.v;
    }
  }
}

extern "C" void kernel_launch(void* const* d_in, const int* in_sizes, int n_in,
                              void* d_out, int out_size, void* d_ws, size_t ws_size,
                              hipStream_t stream) {
  const float* xq = (const float*)d_in[0];
  const float* xk = (const float*)d_in[1];
  const float* xv = (const float*)d_in[2];
  const float* wq = (const float*)d_in[3];
  const float* bq = (const float*)d_in[4];
  const float* wk = (const float*)d_in[5];
  const float* bk = (const float*)d_in[6];
  const float* wv = (const float*)d_in[7];
  const float* bv = (const float*)d_in[8];
  const float* wo = (const float*)d_in[9];
  const float* bo = (const float*)d_in[10];
  ushort* ws = (ushort*)d_ws;

  cvt_all<<<8192, 256, 0, stream>>>(xq, xk, xv, wq, wk, wv, wo, ws);
  gemm_qkv<<<dim3(8, 32, 3), 256, 0, stream>>>(ws, ws, bq, bk, bv);
  attn32<<<dim3(16, 32), 256, 0, stream>>>(ws + QB_O, ws + KB_O, ws + VT_O, ws + CTX_O);
  gemm_out<<<dim3(8, 32), 256, 0, stream>>>(ws + CTX_O, ws + WO_O, bo, (float*)d_out);
}